// Round 7
// baseline (645.283 us; speedup 1.0000x reference)
//
#include <hip/hip_runtime.h>
#include <math.h>

#define N_C 100000
#define HD 128
#define SCAN_CHUNK 1024

typedef short v8s __attribute__((ext_vector_type(8)));
typedef float v4f __attribute__((ext_vector_type(4)));

__device__ __forceinline__ unsigned short f2bf(float f) {
  unsigned int u = __float_as_uint(f);
  u += 0x7fffu + ((u >> 16) & 1u);
  return (unsigned short)(u >> 16);
}

// exact relu on two packed bf16 halves (negative & -0 -> +0)
__device__ __forceinline__ unsigned int relu2(unsigned int u) {
  unsigned int m = ((u & 0x80008000u) >> 15) * 0xFFFFu;
  return u & ~m;
}

// ------------------------------------------------------------------
// fused prep kernels (batched over blockIdx.y)
// ------------------------------------------------------------------
__global__ void count3_kernel(const int* __restrict__ ei_s, int Es,
                              const int* __restrict__ ei_a, int Ea,
                              const int* __restrict__ ei_t, int Et,
                              int* __restrict__ cnt) {
  int e = blockIdx.x * 256 + threadIdx.x;
  int y = blockIdx.y;
  if (y == 0) {
    if (e < Es) atomicAdd(&cnt[ei_s[Es + e]], 1);
  } else if (y == 1) {
    if (e < Ea) atomicAdd(&cnt[N_C + ei_a[Ea + e]], 1);
  } else {
    if (e < Et) atomicAdd(&cnt[2 * N_C + ei_t[Et + e]], 1);
  }
}

__global__ void place3_kernel(const int* __restrict__ ei_s, int Es,
                              const int* __restrict__ ei_a, int Ea,
                              const int* __restrict__ ei_t, int Et,
                              const int* __restrict__ rs_all, int* __restrict__ fill,
                              int* __restrict__ src_s, int* __restrict__ src_a,
                              int* __restrict__ src_t, int n) {
  int e = blockIdx.x * 256 + threadIdx.x;
  int y = blockIdx.y;
  const int* ei; int E; const int* rs; int* fl; int* out;
  if (y == 0)      { ei = ei_s; E = Es; rs = rs_all;               fl = fill;         out = src_s; }
  else if (y == 1) { ei = ei_a; E = Ea; rs = rs_all + (n + 1);     fl = fill + n;     out = src_a; }
  else             { ei = ei_t; E = Et; rs = rs_all + 2 * (n + 1); fl = fill + 2 * n; out = src_t; }
  if (e < E) {
    int d = ei[E + e];
    int p = rs[d] + atomicAdd(&fl[d], 1);
    out[p] = ei[e];
  }
}

// ------------------------------------------------------------------
// 3-phase exclusive scan, batched over 3 arrays via blockIdx.y
// ------------------------------------------------------------------
__global__ __launch_bounds__(256) void scan_phaseA(const int* __restrict__ cnt,
                                                   int* __restrict__ partial,
                                                   float* __restrict__ inv, int n) {
  __shared__ int sdata[256];
  const int y = blockIdx.y;
  const int* c = cnt + y * n;
  float* iv = inv + y * n;
  int base = blockIdx.x * SCAN_CHUNK + threadIdx.x * 4;
  int s = 0;
#pragma unroll
  for (int j = 0; j < 4; ++j) {
    int idx = base + j;
    if (idx < n) {
      int v = c[idx];
      s += v;
      iv[idx] = 1.0f / fmaxf((float)v, 1.0f);
    }
  }
  sdata[threadIdx.x] = s;
  __syncthreads();
  for (int off = 128; off > 0; off >>= 1) {
    if (threadIdx.x < off) sdata[threadIdx.x] += sdata[threadIdx.x + off];
    __syncthreads();
  }
  if (threadIdx.x == 0) partial[y * 128 + blockIdx.x] = sdata[0];
}

__global__ __launch_bounds__(256) void scan_phaseB(int* __restrict__ partial, int nb) {
  __shared__ int sdata[256];
  int* p = partial + blockIdx.y * 128;
  int t = threadIdx.x;
  int v = (t < nb) ? p[t] : 0;
  sdata[t] = v;
  __syncthreads();
  for (int off = 1; off < 256; off <<= 1) {
    int x = (t >= off) ? sdata[t - off] : 0;
    __syncthreads();
    sdata[t] += x;
    __syncthreads();
  }
  if (t < nb) p[t] = sdata[t] - v;
}

__global__ __launch_bounds__(256) void scan_phaseC(const int* __restrict__ cnt,
                                                   const int* __restrict__ partial,
                                                   int* __restrict__ rs_all, int n) {
  __shared__ int sdata[256];
  const int y = blockIdx.y;
  const int* c = cnt + y * n;
  int* rs = rs_all + y * (n + 1);
  int t = threadIdx.x;
  int base = blockIdx.x * SCAN_CHUNK + t * 4;
  int v[4];
  int s = 0;
#pragma unroll
  for (int j = 0; j < 4; ++j) {
    int idx = base + j;
    v[j] = (idx < n) ? c[idx] : 0;
    s += v[j];
  }
  sdata[t] = s;
  __syncthreads();
  for (int off = 1; off < 256; off <<= 1) {
    int x = (t >= off) ? sdata[t - off] : 0;
    __syncthreads();
    sdata[t] += x;
    __syncthreads();
  }
  int run = sdata[t] - s + partial[y * 128 + blockIdx.x];
#pragma unroll
  for (int j = 0; j < 4; ++j) {
    int idx = base + j;
    if (idx < n) rs[idx] = run;
    run += v[j];
  }
}

__global__ void set_totals(int* rs_all, int Es, int Ea, int Et, int n) {
  if (threadIdx.x == 0) {
    rs_all[n] = Es;
    rs_all[(n + 1) + n] = Ea;
    rs_all[2 * (n + 1) + n] = Et;
  }
}

// ------------------------------------------------------------------
// single prep kernel: 8 weight transposes+cvt (y=0..7), biases (y=8),
// packed head weight [16 x 128] bf16 (y=9). grid (128, 10) x 256
// ------------------------------------------------------------------
__global__ void prep_weights(
    const float* __restrict__ c1s_Wl, const float* __restrict__ c1s_Wr,
    const float* __restrict__ c1a_Wr, const float* __restrict__ c1t_Wr,
    const float* __restrict__ c1a_Wl, const float* __restrict__ c1t_Wl,
    const float* __restrict__ c2s_Wl, const float* __restrict__ c2s_Wr,
    const float* __restrict__ c2a_Wr, const float* __restrict__ c2t_Wr,
    const float* __restrict__ c2a_Wl, const float* __restrict__ c2t_Wl,
    const float* __restrict__ c1s_bl, const float* __restrict__ c1a_bl,
    const float* __restrict__ c1t_bl, const float* __restrict__ c2s_bl,
    const float* __restrict__ c2a_bl, const float* __restrict__ c2t_bl,
    const float* __restrict__ Wt, const float* __restrict__ bt,
    const float* __restrict__ Wi, const float* __restrict__ bi,
    const float* __restrict__ Wm, const float* __restrict__ bm,
    unsigned short* __restrict__ Bt_c1s, unsigned short* __restrict__ Bt_W1s,
    unsigned short* __restrict__ Bt_c1a, unsigned short* __restrict__ Bt_c1t,
    unsigned short* __restrict__ Bt_c2s, unsigned short* __restrict__ Bt_W2s,
    unsigned short* __restrict__ Bt_c2a, unsigned short* __restrict__ Bt_c2t,
    unsigned short* __restrict__ Wht,
    float* __restrict__ b1s, float* __restrict__ b2s, float* __restrict__ bh) {
  int y = blockIdx.y;
  int idx = blockIdx.x * 256 + threadIdx.x;
  if (y == 8) {
    if (blockIdx.x == 0) {
      int t = threadIdx.x;
      if (t < 128) b1s[t] = c1s_bl[t] + c1a_bl[t] + c1t_bl[t];
      else b2s[t - 128] = c2s_bl[t - 128] + c2a_bl[t - 128] + c2t_bl[t - 128];
    } else if (blockIdx.x == 1) {
      int t = threadIdx.x;
      if (t < 16) {
        float v = 0.f;
        if (t < 5) v = bt[t];
        else if (t < 9) v = bi[t - 5];
        else if (t < 12) v = bm[t - 9];
        bh[t] = v;
      }
    }
    return;
  }
  if (y == 9) {
    if (idx < 16 * 128) {
      int o = idx >> 7, k = idx & 127;
      float v = 0.f;
      if (o < 5) v = Wt[k * 5 + o];
      else if (o < 9) v = Wi[k * 4 + (o - 5)];
      else if (o < 12) v = Wm[k * 3 + (o - 9)];
      Wht[o * 128 + k] = f2bf(v);
    }
    return;
  }
  int K = (y < 2) ? 256 : 128;
  if (idx >= K * 128) return;
  int k = idx >> 7, n = idx & 127;
  float v;
  unsigned short* out;
  switch (y) {
    case 0: v = c1s_Wl[idx]; out = Bt_c1s; break;
    case 1: v = c1s_Wr[idx] + c1a_Wr[idx] + c1t_Wr[idx]; out = Bt_W1s; break;
    case 2: v = c1a_Wl[idx]; out = Bt_c1a; break;
    case 3: v = c1t_Wl[idx]; out = Bt_c1t; break;
    case 4: v = c2s_Wl[idx]; out = Bt_c2s; break;
    case 5: v = c2s_Wr[idx] + c2a_Wr[idx] + c2t_Wr[idx]; out = Bt_W2s; break;
    case 6: v = c2a_Wl[idx]; out = Bt_c2a; break;
    default: v = c2t_Wl[idx]; out = Bt_c2t; break;
  }
  out[n * K + k] = f2bf(v);
}

// ------------------------------------------------------------------
// MFMA GEMM with register-prefetch pipeline:
//   C0(bf16) = act(A)@B0 [, C1(bf16) = act(A)@B1 + bias1]
// A is fp32 (ABF16=false) or bf16 (ABF16=true). tile 128x128, 4 waves 2x2,
// BK=64, mfma 16x16x32 bf16. Pipeline: store tile k (regs->LDS), barrier,
// issue loads for tile k+1, compute tile k MFMAs (loads in flight).
// A/C1 not __restrict__ — layer-2 call runs in-place (C1 == A).
// ------------------------------------------------------------------
template <int KD, bool DUAL, bool RELUA, bool ABF16>
__global__ __launch_bounds__(256, 2) void mfma_gemm(
    const void* Av, int M,
    const unsigned short* __restrict__ B0t, const unsigned short* __restrict__ B1t,
    unsigned short* __restrict__ C0, unsigned short* C1,
    const float* __restrict__ bias1) {
  constexpr int AST = 72;
  __shared__ unsigned short As[128 * AST];
  __shared__ unsigned short Bs0[128 * AST];
  __shared__ unsigned short Bs1[DUAL ? 128 * AST : 8];

  const int t = threadIdx.x;
  const int wave = t >> 6, lane = t & 63;
  const int wm = (wave & 1) * 64;
  const int wn = (wave >> 1) * 64;
  const int m0 = blockIdx.x * 128;
  const int lrow = lane & 15, lq = lane >> 4;

  const float* Af = (const float*)Av;
  const unsigned short* Ab = (const unsigned short*)Av;

  v4f acc0[4][4];
  v4f acc1[DUAL ? 4 : 1][DUAL ? 4 : 1];
#pragma unroll
  for (int i = 0; i < 4; ++i)
#pragma unroll
    for (int j = 0; j < 4; ++j) acc0[i][j] = (v4f)(0.f);
  if constexpr (DUAL) {
#pragma unroll
    for (int i = 0; i < 4; ++i)
#pragma unroll
      for (int j = 0; j < 4; ++j) acc1[i][j] = (v4f)(0.f);
  }

  // prefetch registers
  float4 pa4[ABF16 ? 1 : 8];
  uint4 pa8[ABF16 ? 4 : 1];
  uint4 pb0[4];
  uint4 pb1[DUAL ? 4 : 1];

  auto loadA = [&](int k0) {
    if constexpr (ABF16) {
#pragma unroll
      for (int j = 0; j < 4; ++j) {
        int idx = j * 256 + t;
        int row = idx >> 3, k8 = idx & 7;
        int gr = m0 + row;
        uint4 v = make_uint4(0, 0, 0, 0);
        if (gr < M) v = *(const uint4*)(Ab + (size_t)gr * KD + k0 + k8 * 8);
        pa8[j] = v;
      }
    } else {
#pragma unroll
      for (int j = 0; j < 8; ++j) {
        int idx = j * 256 + t;
        int row = idx >> 4, c4 = idx & 15;
        int gr = m0 + row;
        float4 v = make_float4(0.f, 0.f, 0.f, 0.f);
        if (gr < M) v = *(const float4*)(Af + (size_t)gr * KD + k0 + c4 * 4);
        pa4[j] = v;
      }
    }
  };
  auto loadB = [&](int k0) {
#pragma unroll
    for (int j = 0; j < 4; ++j) {
      int idx = j * 256 + t;
      int row = idx >> 3, k8 = idx & 7;
      pb0[j] = *(const uint4*)(B0t + (size_t)row * KD + k0 + k8 * 8);
      if constexpr (DUAL)
        pb1[j] = *(const uint4*)(B1t + (size_t)row * KD + k0 + k8 * 8);
    }
  };
  auto storeAB = [&]() {
    if constexpr (ABF16) {
#pragma unroll
      for (int j = 0; j < 4; ++j) {
        int idx = j * 256 + t;
        int row = idx >> 3, k8 = idx & 7;
        uint4 v = pa8[j];
        if constexpr (RELUA) {
          v.x = relu2(v.x); v.y = relu2(v.y); v.z = relu2(v.z); v.w = relu2(v.w);
        }
        *(uint4*)&As[row * AST + k8 * 8] = v;
      }
    } else {
#pragma unroll
      for (int j = 0; j < 8; ++j) {
        int idx = j * 256 + t;
        int row = idx >> 4, c4 = idx & 15;
        float4 v = pa4[j];
        if constexpr (RELUA) {
          v.x = fmaxf(v.x, 0.f); v.y = fmaxf(v.y, 0.f);
          v.z = fmaxf(v.z, 0.f); v.w = fmaxf(v.w, 0.f);
        }
        unsigned short* d = &As[row * AST + c4 * 4];
        d[0] = f2bf(v.x); d[1] = f2bf(v.y); d[2] = f2bf(v.z); d[3] = f2bf(v.w);
      }
    }
#pragma unroll
    for (int j = 0; j < 4; ++j) {
      int idx = j * 256 + t;
      int row = idx >> 3, k8 = idx & 7;
      *(uint4*)&Bs0[row * AST + k8 * 8] = pb0[j];
      if constexpr (DUAL) *(uint4*)&Bs1[row * AST + k8 * 8] = pb1[j];
    }
  };

  loadA(0);
  loadB(0);
#pragma unroll
  for (int k0 = 0; k0 < KD; k0 += 64) {
    if (k0) __syncthreads();
    storeAB();
    __syncthreads();
    if (k0 + 64 < KD) {
      loadA(k0 + 64);
      loadB(k0 + 64);
    }
#pragma unroll
    for (int ks = 0; ks < 2; ++ks) {
      v8s af[4];
#pragma unroll
      for (int mt = 0; mt < 4; ++mt)
        af[mt] = *(const v8s*)&As[(wm + mt * 16 + lrow) * AST + ks * 32 + lq * 8];
#pragma unroll
      for (int cb = 0; cb < 4; ++cb) {
        v8s b0 = *(const v8s*)&Bs0[(wn + cb * 16 + lrow) * AST + ks * 32 + lq * 8];
#pragma unroll
        for (int mt = 0; mt < 4; ++mt)
          acc0[mt][cb] = __builtin_amdgcn_mfma_f32_16x16x32_bf16(af[mt], b0, acc0[mt][cb], 0, 0, 0);
        if constexpr (DUAL) {
          v8s b1 = *(const v8s*)&Bs1[(wn + cb * 16 + lrow) * AST + ks * 32 + lq * 8];
#pragma unroll
          for (int mt = 0; mt < 4; ++mt)
            acc1[mt][cb] = __builtin_amdgcn_mfma_f32_16x16x32_bf16(af[mt], b1, acc1[mt][cb], 0, 0, 0);
        }
      }
    }
  }

  float bv[4] = {0.f, 0.f, 0.f, 0.f};
  if constexpr (DUAL) {
#pragma unroll
    for (int cb = 0; cb < 4; ++cb) bv[cb] = bias1[wn + cb * 16 + lrow];
  }
#pragma unroll
  for (int mt = 0; mt < 4; ++mt) {
#pragma unroll
    for (int r = 0; r < 4; ++r) {
      int gr = m0 + wm + mt * 16 + lq * 4 + r;
      if (gr < M) {
#pragma unroll
        for (int cb = 0; cb < 4; ++cb) {
          int gc = wn + cb * 16 + lrow;
          C0[(size_t)gr * 128 + gc] = f2bf(acc0[mt][cb][r]);
          if constexpr (DUAL) C1[(size_t)gr * 128 + gc] = f2bf(acc1[mt][cb][r] + bv[cb]);
        }
      }
    }
  }
}

// ------------------------------------------------------------------
// fused CSR gather, quarter-wave per edge; h is bf16 (RMW by quarter 0)
// ------------------------------------------------------------------
__global__ __launch_bounds__(256) void gather_kernel(
    const unsigned short* __restrict__ ys, const unsigned short* __restrict__ ya,
    const unsigned short* __restrict__ yt,
    const int* __restrict__ rs_all,
    const int* __restrict__ src_s, const int* __restrict__ src_a,
    const int* __restrict__ src_t,
    const float* __restrict__ inv, unsigned short* h, int M) {
  int row = blockIdx.x * 4 + (threadIdx.x >> 6);
  if (row >= M) return;
  const int lane = threadIdx.x & 63;
  const int q = lane >> 4;
  const int col = (lane & 15) * 8;
  const int NP = M + 1;

  int b0 = rs_all[row],          e0 = rs_all[row + 1];
  int b1 = rs_all[NP + row],     e1 = rs_all[NP + row + 1];
  int b2 = rs_all[2 * NP + row], e2 = rs_all[2 * NP + row + 1];
  float sc0 = inv[row], sc1 = inv[M + row], sc2 = inv[2 * M + row];

  float acc[8];
#pragma unroll
  for (int j = 0; j < 8; ++j) acc[j] = 0.f;

  auto seg = [&](const unsigned short* __restrict__ y, const int* __restrict__ src,
                 int b, int e, float sc) {
    float s[8];
#pragma unroll
    for (int j = 0; j < 8; ++j) s[j] = 0.f;
    for (int i = b + q; i < e; i += 4) {
      int si = src[i];
      uint4 v = *(const uint4*)(y + (size_t)si * HD + col);
      s[0] += __uint_as_float(v.x << 16);
      s[1] += __uint_as_float(v.x & 0xffff0000u);
      s[2] += __uint_as_float(v.y << 16);
      s[3] += __uint_as_float(v.y & 0xffff0000u);
      s[4] += __uint_as_float(v.z << 16);
      s[5] += __uint_as_float(v.z & 0xffff0000u);
      s[6] += __uint_as_float(v.w << 16);
      s[7] += __uint_as_float(v.w & 0xffff0000u);
    }
#pragma unroll
    for (int j = 0; j < 8; ++j) acc[j] += s[j] * sc;
  };
  seg(ys, src_s, b0, e0, sc0);
  seg(ya, src_a, b1, e1, sc1);
  seg(yt, src_t, b2, e2, sc2);

#pragma unroll
  for (int j = 0; j < 8; ++j) {
    acc[j] += __shfl_xor(acc[j], 16);
    acc[j] += __shfl_xor(acc[j], 32);
  }
  if (q == 0) {
    uint4 hv = *(uint4*)(h + (size_t)row * HD + col);
    auto upd = [&](unsigned int u, float a0, float a1) {
      float lo = __uint_as_float(u << 16) + a0;
      float hi = __uint_as_float(u & 0xffff0000u) + a1;
      return (unsigned int)f2bf(lo) | ((unsigned int)f2bf(hi) << 16);
    };
    hv.x = upd(hv.x, acc[0], acc[1]);
    hv.y = upd(hv.y, acc[2], acc[3]);
    hv.z = upd(hv.z, acc[4], acc[5]);
    hv.w = upd(hv.w, acc[6], acc[7]);
    *(uint4*)(h + (size_t)row * HD + col) = hv;
  }
}

// ------------------------------------------------------------------
// heads pass 1: P[M x 16] = relu(h2) @ Wht^T + bh  (h2 bf16)
// 64 rows per block (4 waves x 16 rows), single LDS staging
// ------------------------------------------------------------------
__global__ __launch_bounds__(256, 4) void heads_gemm(
    const unsigned short* __restrict__ h2b, int M,
    const unsigned short* __restrict__ Wht, const float* __restrict__ bh,
    float* __restrict__ P) {
  constexpr int AST_H = 136;
  __shared__ unsigned short As[64 * AST_H];
  const int t = threadIdx.x;
  const int wave = t >> 6, lane = t & 63;
  const int m0 = blockIdx.x * 64;
  const int lrow = lane & 15, lq = lane >> 4;

#pragma unroll
  for (int j = 0; j < 4; ++j) {
    int idx = j * 256 + t;       // 1024 uint4 slots = 64 rows x 16
    int row = idx >> 4;
    int c8 = idx & 15;
    int gr = m0 + row;
    uint4 v = make_uint4(0, 0, 0, 0);
    if (gr < M) v = *(const uint4*)(h2b + (size_t)gr * 128 + c8 * 8);
    v.x = relu2(v.x); v.y = relu2(v.y); v.z = relu2(v.z); v.w = relu2(v.w);
    *(uint4*)&As[row * AST_H + c8 * 8] = v;
  }
  __syncthreads();

  v4f acc = (v4f)(0.f);
#pragma unroll
  for (int ks = 0; ks < 4; ++ks) {
    v8s a = *(const v8s*)&As[(wave * 16 + lrow) * AST_H + ks * 32 + lq * 8];
    v8s b = *(const v8s*)(Wht + lrow * 128 + ks * 32 + lq * 8);
    acc = __builtin_amdgcn_mfma_f32_16x16x32_bf16(a, b, acc, 0, 0, 0);
  }
  float bv = bh[lrow];
#pragma unroll
  for (int r = 0; r < 4; ++r) {
    int gr = m0 + wave * 16 + lq * 4 + r;
    if (gr < M) P[(size_t)gr * 16 + lrow] = acc[r] + bv;
  }
}

// ------------------------------------------------------------------
// heads pass 2: thread-per-row sigmoid/softmax + impl head, scatter out
// ------------------------------------------------------------------
__global__ __launch_bounds__(256) void heads_epi(
    const float* __restrict__ P, const float* __restrict__ Wm,
    float* __restrict__ out_t, float* __restrict__ out_i,
    float* __restrict__ out_m, int M) {
  int row = blockIdx.x * 256 + threadIdx.x;
  if (row >= M) return;
  float4 p0 = *(const float4*)(P + (size_t)row * 16);
  float4 p1 = *(const float4*)(P + (size_t)row * 16 + 4);
  float4 p2 = *(const float4*)(P + (size_t)row * 16 + 8);
  float t_[5] = {p0.x, p0.y, p0.z, p0.w, p1.x};
  float i_[4] = {p1.y, p1.z, p1.w, p2.x};
  float mb[3] = {p2.y, p2.z, p2.w};
  float tp[5];
#pragma unroll
  for (int o = 0; o < 5; ++o) tp[o] = 1.f / (1.f + __expf(-t_[o]));
  float mx = fmaxf(fmaxf(i_[0], i_[1]), fmaxf(i_[2], i_[3]));
  float ex[4], es = 0.f;
#pragma unroll
  for (int o = 0; o < 4; ++o) { ex[o] = __expf(i_[o] - mx); es += ex[o]; }
  float inv_es = 1.f / es;
  float ml[3];
#pragma unroll
  for (int o = 0; o < 3; ++o) {
    float v = mb[o];
#pragma unroll
    for (int j = 0; j < 5; ++j) v += tp[j] * Wm[(128 + j) * 3 + o];
#pragma unroll
    for (int j = 0; j < 4; ++j) v += (ex[j] * inv_es) * Wm[(133 + j) * 3 + o];
    ml[o] = v;
  }
#pragma unroll
  for (int o = 0; o < 5; ++o) out_t[(size_t)row * 5 + o] = t_[o];
#pragma unroll
  for (int o = 0; o < 4; ++o) out_i[(size_t)row * 4 + o] = i_[o];
#pragma unroll
  for (int o = 0; o < 3; ++o) out_m[(size_t)row * 3 + o] = ml[o];
}

// ------------------------------------------------------------------
extern "C" void kernel_launch(void* const* d_in, const int* in_sizes, int n_in,
                              void* d_out, int out_size, void* d_ws, size_t ws_size,
                              hipStream_t stream) {
  const float* x_comment = (const float*)d_in[0];
  const float* x_topic   = (const float*)d_in[1];
  const float* x_claim   = (const float*)d_in[2];
  const float* c1s_Wl = (const float*)d_in[3];
  const float* c1s_bl = (const float*)d_in[4];
  const float* c1s_Wr = (const float*)d_in[5];
  const float* c1a_Wl = (const float*)d_in[6];
  const float* c1a_bl = (const float*)d_in[7];
  const float* c1a_Wr = (const float*)d_in[8];
  const float* c1t_Wl = (const float*)d_in[9];
  const float* c1t_bl = (const float*)d_in[10];
  const float* c1t_Wr = (const float*)d_in[11];
  const float* c2s_Wl = (const float*)d_in[12];
  const float* c2s_bl = (const float*)d_in[13];
  const float* c2s_Wr = (const float*)d_in[14];
  const float* c2a_Wl = (const float*)d_in[15];
  const float* c2a_bl = (const float*)d_in[16];
  const float* c2a_Wr = (const float*)d_in[17];
  const float* c2t_Wl = (const float*)d_in[18];
  const float* c2t_bl = (const float*)d_in[19];
  const float* c2t_Wr = (const float*)d_in[20];
  const float* Wt = (const float*)d_in[21];
  const float* bt = (const float*)d_in[22];
  const float* Wi = (const float*)d_in[23];
  const float* bi = (const float*)d_in[24];
  const float* Wm = (const float*)d_in[25];
  const float* bm = (const float*)d_in[26];
  const int* ei_sim = (const int*)d_in[27];
  const int* ei_ab  = (const int*)d_in[28];
  const int* ei_tg  = (const int*)d_in[29];

  const int E_sim = in_sizes[27] / 2;
  const int E_ab  = in_sizes[28] / 2;
  const int E_tg  = in_sizes[29] / 2;
  const int N_T = in_sizes[1] / 128;
  const int N_CL = in_sizes[2] / 128;

  float* ws = (float*)d_ws;
  // workspace (float-element offsets)
  unsigned short* h1 = (unsigned short*)ws;                // 100000*128 bf16 (6.4M floats)
  unsigned short* y_s = (unsigned short*)(ws + 12800000);  // 100000*128 bf16
  unsigned short* y_a = (unsigned short*)(ws + 19200000);  // 5000*128 bf16
  unsigned short* y_t = (unsigned short*)(ws + 19520000);  // 20000*128 bf16
  int*   cnt    = (int*)(ws + 20800000);                   // 3*N_C
  float* inv    = ws + 21100000;                           // 3*N_C
  int*   rs_all = (int*)(ws + 21400000);                   // 3*(N_C+1)
  int*   src_s  = (int*)(ws + 21700016);                   // E_sim
  int*   src_a  = (int*)(ws + 22300016);                   // E_ab
  int*   src_t  = (int*)(ws + 22600016);                   // E_tg
  int*   part   = (int*)(ws + 22900016);                   // 3*128
  float* b1s    = ws + 22900416;
  float* b2s    = ws + 22900544;
  unsigned short* Bt_c1s = (unsigned short*)(ws + 22900672);  // 128x256
  unsigned short* Bt_W1s = Bt_c1s + 32768;                    // 128x256
  unsigned short* Bt_c1a = Bt_W1s + 32768;                    // 128x128
  unsigned short* Bt_c1t = Bt_c1a + 16384;
  unsigned short* Bt_c2s = Bt_c1t + 16384;
  unsigned short* Bt_W2s = Bt_c2s + 16384;
  unsigned short* Bt_c2a = Bt_W2s + 16384;
  unsigned short* Bt_c2t = Bt_c2a + 16384;
  float* P      = ws + 23000000;                              // 100000*16 fp32
  unsigned short* Wht = (unsigned short*)(ws + 24600000);     // 16x128 bf16
  float* bh     = ws + 24601100;                              // 16

  const int nbS = (N_C + SCAN_CHUNK - 1) / SCAN_CHUNK;
  const int ebx = (E_sim + 255) / 256;

  // ---- weight prep ----
  prep_weights<<<dim3(128, 10), 256, 0, stream>>>(
      c1s_Wl, c1s_Wr, c1a_Wr, c1t_Wr, c1a_Wl, c1t_Wl,
      c2s_Wl, c2s_Wr, c2a_Wr, c2t_Wr, c2a_Wl, c2t_Wl,
      c1s_bl, c1a_bl, c1t_bl, c2s_bl, c2a_bl, c2t_bl,
      Wt, bt, Wi, bi, Wm, bm,
      Bt_c1s, Bt_W1s, Bt_c1a, Bt_c1t, Bt_c2s, Bt_W2s, Bt_c2a, Bt_c2t,
      Wht, b1s, b2s, bh);

  // ---- degree histogram + CSR build ----
  hipMemsetAsync(cnt, 0, 3 * N_C * sizeof(int), stream);
  count3_kernel<<<dim3(ebx, 3), 256, 0, stream>>>(ei_sim, E_sim, ei_ab, E_ab, ei_tg, E_tg, cnt);
  scan_phaseA<<<dim3(nbS, 3), 256, 0, stream>>>(cnt, part, inv, N_C);
  scan_phaseB<<<dim3(1, 3), 256, 0, stream>>>(part, nbS);
  scan_phaseC<<<dim3(nbS, 3), 256, 0, stream>>>(cnt, part, rs_all, N_C);
  set_totals<<<1, 64, 0, stream>>>(rs_all, E_sim, E_ab, E_tg, N_C);
  hipMemsetAsync(cnt, 0, 3 * N_C * sizeof(int), stream);
  place3_kernel<<<dim3(ebx, 3), 256, 0, stream>>>(
      ei_sim, E_sim, ei_ab, E_ab, ei_tg, E_tg, rs_all, cnt, src_s, src_a, src_t, N_C);

  // ---------------- layer 1 ----------------
  mfma_gemm<256, true, false, false><<<(N_C + 127) / 128, 256, 0, stream>>>(
      x_comment, N_C, Bt_c1s, Bt_W1s, y_s, h1, b1s);
  mfma_gemm<128, false, false, false><<<(N_T + 127) / 128, 256, 0, stream>>>(
      x_topic, N_T, Bt_c1a, nullptr, y_a, nullptr, nullptr);
  mfma_gemm<128, false, false, false><<<(N_CL + 127) / 128, 256, 0, stream>>>(
      x_claim, N_CL, Bt_c1t, nullptr, y_t, nullptr, nullptr);

  gather_kernel<<<(N_C + 3) / 4, 256, 0, stream>>>(
      y_s, y_a, y_t, rs_all, src_s, src_a, src_t, inv, h1, N_C);

  // ---------------- layer 2 (in-place h1 -> h2, bf16) ----------------
  mfma_gemm<128, true, true, true><<<(N_C + 127) / 128, 256, 0, stream>>>(
      h1, N_C, Bt_c2s, Bt_W2s, y_s, h1, b2s);
  mfma_gemm<128, false, false, false><<<(N_T + 127) / 128, 256, 0, stream>>>(
      x_topic, N_T, Bt_c2a, nullptr, y_a, nullptr, nullptr);
  mfma_gemm<128, false, false, false><<<(N_CL + 127) / 128, 256, 0, stream>>>(
      x_claim, N_CL, Bt_c2t, nullptr, y_t, nullptr, nullptr);

  gather_kernel<<<(N_C + 3) / 4, 256, 0, stream>>>(
      y_s, y_a, y_t, rs_all, src_s, src_a, src_t, inv, h1, N_C);

  // ---------------- heads ----------------
  float* out = (float*)d_out;
  heads_gemm<<<(N_C + 63) / 64, 256, 0, stream>>>(h1, N_C, Wht, bh, P);
  heads_epi<<<(N_C + 255) / 256, 256, 0, stream>>>(
      P, Wm, out, out + (size_t)N_C * 5, out + (size_t)N_C * 9, N_C);
}

// Round 8
// 537.649 us; speedup vs baseline: 1.2002x; 1.2002x over previous
//
#include <hip/hip_runtime.h>
#include <math.h>

#define N_C 100000
#define HD 128
#define SCAN_CHUNK 1024
#define AST 72

typedef short v8s __attribute__((ext_vector_type(8)));
typedef float v4f __attribute__((ext_vector_type(4)));

__device__ __forceinline__ unsigned short f2bf(float f) {
  unsigned int u = __float_as_uint(f);
  u += 0x7fffu + ((u >> 16) & 1u);
  return (unsigned short)(u >> 16);
}

// exact relu on two packed bf16 halves (negative & -0 -> +0)
__device__ __forceinline__ unsigned int relu2(unsigned int u) {
  unsigned int m = ((u & 0x80008000u) >> 15) * 0xFFFFu;
  return u & ~m;
}

// ------------------------------------------------------------------
// fused prep kernels
// ------------------------------------------------------------------
__global__ void count3_kernel(const int* __restrict__ ei_s, int Es,
                              const int* __restrict__ ei_a, int Ea,
                              const int* __restrict__ ei_t, int Et,
                              int* __restrict__ cnt) {
  int e = blockIdx.x * 256 + threadIdx.x;
  int y = blockIdx.y;
  if (y == 0) {
    if (e < Es) atomicAdd(&cnt[ei_s[Es + e]], 1);
  } else if (y == 1) {
    if (e < Ea) atomicAdd(&cnt[N_C + ei_a[Ea + e]], 1);
  } else {
    if (e < Et) atomicAdd(&cnt[2 * N_C + ei_t[Et + e]], 1);
  }
}

__global__ void place3_kernel(const int* __restrict__ ei_s, int Es,
                              const int* __restrict__ ei_a, int Ea,
                              const int* __restrict__ ei_t, int Et,
                              const int* __restrict__ rs_all, int* __restrict__ fill,
                              int* __restrict__ src_s, int* __restrict__ src_a,
                              int* __restrict__ src_t, int n) {
  int e = blockIdx.x * 256 + threadIdx.x;
  int y = blockIdx.y;
  const int* ei; int E; const int* rs; int* fl; int* out;
  if (y == 0)      { ei = ei_s; E = Es; rs = rs_all;               fl = fill;         out = src_s; }
  else if (y == 1) { ei = ei_a; E = Ea; rs = rs_all + (n + 1);     fl = fill + n;     out = src_a; }
  else             { ei = ei_t; E = Et; rs = rs_all + 2 * (n + 1); fl = fill + 2 * n; out = src_t; }
  if (e < E) {
    int d = ei[E + e];
    int p = rs[d] + atomicAdd(&fl[d], 1);
    out[p] = ei[e];
  }
}

// ------------------------------------------------------------------
// 3-phase exclusive scan (batched over blockIdx.y); phaseA emits inv,
// phaseC zeroes cnt after reading (so place3 can reuse it as fill).
// ------------------------------------------------------------------
__global__ __launch_bounds__(256) void scan_phaseA(const int* __restrict__ cnt,
                                                   int* __restrict__ partial,
                                                   float* __restrict__ inv, int n) {
  __shared__ int sdata[256];
  const int y = blockIdx.y;
  const int* c = cnt + y * n;
  float* iv = inv + y * n;
  int base = blockIdx.x * SCAN_CHUNK + threadIdx.x * 4;
  int s = 0;
#pragma unroll
  for (int j = 0; j < 4; ++j) {
    int idx = base + j;
    if (idx < n) {
      int v = c[idx];
      s += v;
      iv[idx] = 1.0f / fmaxf((float)v, 1.0f);
    }
  }
  sdata[threadIdx.x] = s;
  __syncthreads();
  for (int off = 128; off > 0; off >>= 1) {
    if (threadIdx.x < off) sdata[threadIdx.x] += sdata[threadIdx.x + off];
    __syncthreads();
  }
  if (threadIdx.x == 0) partial[y * 128 + blockIdx.x] = sdata[0];
}

__global__ __launch_bounds__(256) void scan_phaseB(int* __restrict__ partial, int nb) {
  __shared__ int sdata[256];
  int* p = partial + blockIdx.y * 128;
  int t = threadIdx.x;
  int v = (t < nb) ? p[t] : 0;
  sdata[t] = v;
  __syncthreads();
  for (int off = 1; off < 256; off <<= 1) {
    int x = (t >= off) ? sdata[t - off] : 0;
    __syncthreads();
    sdata[t] += x;
    __syncthreads();
  }
  if (t < nb) p[t] = sdata[t] - v;
}

__global__ __launch_bounds__(256) void scan_phaseC(int* __restrict__ cnt,
                                                   const int* __restrict__ partial,
                                                   int* __restrict__ rs_all, int n) {
  __shared__ int sdata[256];
  const int y = blockIdx.y;
  int* c = cnt + y * n;
  int* rs = rs_all + y * (n + 1);
  int t = threadIdx.x;
  int base = blockIdx.x * SCAN_CHUNK + t * 4;
  int v[4];
  int s = 0;
#pragma unroll
  for (int j = 0; j < 4; ++j) {
    int idx = base + j;
    v[j] = (idx < n) ? c[idx] : 0;
    s += v[j];
    if (idx < n) c[idx] = 0;  // reuse as fill in place3
  }
  sdata[t] = s;
  __syncthreads();
  for (int off = 1; off < 256; off <<= 1) {
    int x = (t >= off) ? sdata[t - off] : 0;
    __syncthreads();
    sdata[t] += x;
    __syncthreads();
  }
  int run = sdata[t] - s + partial[y * 128 + blockIdx.x];
#pragma unroll
  for (int j = 0; j < 4; ++j) {
    int idx = base + j;
    if (idx < n) rs[idx] = run;
    run += v[j];
  }
}

__global__ void set_totals(int* rs_all, int Es, int Ea, int Et, int n) {
  if (threadIdx.x == 0) {
    rs_all[n] = Es;
    rs_all[(n + 1) + n] = Ea;
    rs_all[2 * (n + 1) + n] = Et;
  }
}

// ------------------------------------------------------------------
// single prep kernel: weight transposes+cvt (y=0..7), biases (y=8),
// packed head weight (y=9). grid (128, 10) x 256
// ------------------------------------------------------------------
__global__ void prep_weights(
    const float* __restrict__ c1s_Wl, const float* __restrict__ c1s_Wr,
    const float* __restrict__ c1a_Wr, const float* __restrict__ c1t_Wr,
    const float* __restrict__ c1a_Wl, const float* __restrict__ c1t_Wl,
    const float* __restrict__ c2s_Wl, const float* __restrict__ c2s_Wr,
    const float* __restrict__ c2a_Wr, const float* __restrict__ c2t_Wr,
    const float* __restrict__ c2a_Wl, const float* __restrict__ c2t_Wl,
    const float* __restrict__ c1s_bl, const float* __restrict__ c1a_bl,
    const float* __restrict__ c1t_bl, const float* __restrict__ c2s_bl,
    const float* __restrict__ c2a_bl, const float* __restrict__ c2t_bl,
    const float* __restrict__ Wt, const float* __restrict__ bt,
    const float* __restrict__ Wi, const float* __restrict__ bi,
    const float* __restrict__ Wm, const float* __restrict__ bm,
    unsigned short* __restrict__ Bt_c1s, unsigned short* __restrict__ Bt_W1s,
    unsigned short* __restrict__ Bt_c1a, unsigned short* __restrict__ Bt_c1t,
    unsigned short* __restrict__ Bt_c2s, unsigned short* __restrict__ Bt_W2s,
    unsigned short* __restrict__ Bt_c2a, unsigned short* __restrict__ Bt_c2t,
    unsigned short* __restrict__ Wht,
    float* __restrict__ b1s, float* __restrict__ b2s, float* __restrict__ bh) {
  int y = blockIdx.y;
  int idx = blockIdx.x * 256 + threadIdx.x;
  if (y == 8) {
    if (blockIdx.x == 0) {
      int t = threadIdx.x;
      if (t < 128) b1s[t] = c1s_bl[t] + c1a_bl[t] + c1t_bl[t];
      else b2s[t - 128] = c2s_bl[t - 128] + c2a_bl[t - 128] + c2t_bl[t - 128];
    } else if (blockIdx.x == 1) {
      int t = threadIdx.x;
      if (t < 16) {
        float v = 0.f;
        if (t < 5) v = bt[t];
        else if (t < 9) v = bi[t - 5];
        else if (t < 12) v = bm[t - 9];
        bh[t] = v;
      }
    }
    return;
  }
  if (y == 9) {
    if (idx < 16 * 128) {
      int o = idx >> 7, k = idx & 127;
      float v = 0.f;
      if (o < 5) v = Wt[k * 5 + o];
      else if (o < 9) v = Wi[k * 4 + (o - 5)];
      else if (o < 12) v = Wm[k * 3 + (o - 9)];
      Wht[o * 128 + k] = f2bf(v);
    }
    return;
  }
  int K = (y < 2) ? 256 : 128;
  if (idx >= K * 128) return;
  int k = idx >> 7, n = idx & 127;
  float v;
  unsigned short* out;
  switch (y) {
    case 0: v = c1s_Wl[idx]; out = Bt_c1s; break;
    case 1: v = c1s_Wr[idx] + c1a_Wr[idx] + c1t_Wr[idx]; out = Bt_W1s; break;
    case 2: v = c1a_Wl[idx]; out = Bt_c1a; break;
    case 3: v = c1t_Wl[idx]; out = Bt_c1t; break;
    case 4: v = c2s_Wl[idx]; out = Bt_c2s; break;
    case 5: v = c2s_Wr[idx] + c2a_Wr[idx] + c2t_Wr[idx]; out = Bt_W2s; break;
    case 6: v = c2a_Wl[idx]; out = Bt_c2a; break;
    default: v = c2t_Wl[idx]; out = Bt_c2t; break;
  }
  out[n * K + k] = f2bf(v);
}

// ------------------------------------------------------------------
// GEMM body (round-6 two-barrier staging, no reg prefetch):
//   C0(bf16) = act(A)@B0 [, C1(bf16) = act(A)@B1 + bias1]
// A fp32 (ABF16=false) or bf16 (ABF16=true). tile 128x128, 4 waves 2x2,
// BK=64, mfma 16x16x32 bf16. Shared arrays passed in (dynamic LDS).
// A/C1 may alias (layer-2 in-place): block reads only its own 128 rows,
// writes them only in epilogue.
// ------------------------------------------------------------------
template <int KD, bool DUAL, bool RELUA, bool ABF16>
__device__ __forceinline__ void gemm_body(
    int bx, unsigned short* As, unsigned short* Bs0, unsigned short* Bs1,
    const void* Av, int M,
    const unsigned short* __restrict__ B0t, const unsigned short* __restrict__ B1t,
    unsigned short* __restrict__ C0, unsigned short* C1,
    const float* __restrict__ bias1) {
  const int t = threadIdx.x;
  const int wave = t >> 6, lane = t & 63;
  const int wm = (wave & 1) * 64;
  const int wn = (wave >> 1) * 64;
  const int m0 = bx * 128;
  const int lrow = lane & 15, lq = lane >> 4;

  const float* Af = (const float*)Av;
  const unsigned short* Ab = (const unsigned short*)Av;

  v4f acc0[4][4];
  v4f acc1[DUAL ? 4 : 1][DUAL ? 4 : 1];
#pragma unroll
  for (int i = 0; i < 4; ++i)
#pragma unroll
    for (int j = 0; j < 4; ++j) acc0[i][j] = (v4f)(0.f);
  if constexpr (DUAL) {
#pragma unroll
    for (int i = 0; i < 4; ++i)
#pragma unroll
      for (int j = 0; j < 4; ++j) acc1[i][j] = (v4f)(0.f);
  }

  for (int k0 = 0; k0 < KD; k0 += 64) {
    // ---- stage A tile ----
    if constexpr (ABF16) {
#pragma unroll
      for (int j = 0; j < 4; ++j) {
        int idx = j * 256 + t;
        int row = idx >> 3, k8 = idx & 7;
        int gr = m0 + row;
        uint4 v = make_uint4(0, 0, 0, 0);
        if (gr < M) v = *(const uint4*)(Ab + (size_t)gr * KD + k0 + k8 * 8);
        if constexpr (RELUA) {
          v.x = relu2(v.x); v.y = relu2(v.y); v.z = relu2(v.z); v.w = relu2(v.w);
        }
        *(uint4*)&As[row * AST + k8 * 8] = v;
      }
    } else {
#pragma unroll
      for (int j = 0; j < 8; ++j) {
        int idx = j * 256 + t;
        int row = idx >> 4, c4 = idx & 15;
        int gr = m0 + row;
        float4 v = make_float4(0.f, 0.f, 0.f, 0.f);
        if (gr < M) v = *(const float4*)(Af + (size_t)gr * KD + k0 + c4 * 4);
        if constexpr (RELUA) {
          v.x = fmaxf(v.x, 0.f); v.y = fmaxf(v.y, 0.f);
          v.z = fmaxf(v.z, 0.f); v.w = fmaxf(v.w, 0.f);
        }
        unsigned short* d = &As[row * AST + c4 * 4];
        d[0] = f2bf(v.x); d[1] = f2bf(v.y); d[2] = f2bf(v.z); d[3] = f2bf(v.w);
      }
    }
    // ---- stage B tiles ----
#pragma unroll
    for (int j = 0; j < 4; ++j) {
      int idx = j * 256 + t;
      int row = idx >> 3, k8 = idx & 7;
      *(uint4*)&Bs0[row * AST + k8 * 8] =
          *(const uint4*)(B0t + (size_t)row * KD + k0 + k8 * 8);
      if constexpr (DUAL)
        *(uint4*)&Bs1[row * AST + k8 * 8] =
            *(const uint4*)(B1t + (size_t)row * KD + k0 + k8 * 8);
    }
    __syncthreads();

#pragma unroll
    for (int ks = 0; ks < 2; ++ks) {
      v8s af[4];
#pragma unroll
      for (int mt = 0; mt < 4; ++mt)
        af[mt] = *(const v8s*)&As[(wm + mt * 16 + lrow) * AST + ks * 32 + lq * 8];
#pragma unroll
      for (int cb = 0; cb < 4; ++cb) {
        v8s b0 = *(const v8s*)&Bs0[(wn + cb * 16 + lrow) * AST + ks * 32 + lq * 8];
#pragma unroll
        for (int mt = 0; mt < 4; ++mt)
          acc0[mt][cb] = __builtin_amdgcn_mfma_f32_16x16x32_bf16(af[mt], b0, acc0[mt][cb], 0, 0, 0);
        if constexpr (DUAL) {
          v8s b1 = *(const v8s*)&Bs1[(wn + cb * 16 + lrow) * AST + ks * 32 + lq * 8];
#pragma unroll
          for (int mt = 0; mt < 4; ++mt)
            acc1[mt][cb] = __builtin_amdgcn_mfma_f32_16x16x32_bf16(af[mt], b1, acc1[mt][cb], 0, 0, 0);
        }
      }
    }
    __syncthreads();
  }

  float bv[4] = {0.f, 0.f, 0.f, 0.f};
  if constexpr (DUAL) {
#pragma unroll
    for (int cb = 0; cb < 4; ++cb) bv[cb] = bias1[wn + cb * 16 + lrow];
  }
#pragma unroll
  for (int mt = 0; mt < 4; ++mt) {
#pragma unroll
    for (int r = 0; r < 4; ++r) {
      int gr = m0 + wm + mt * 16 + lq * 4 + r;
      if (gr < M) {
#pragma unroll
        for (int cb = 0; cb < 4; ++cb) {
          int gc = wn + cb * 16 + lrow;
          C0[(size_t)gr * 128 + gc] = f2bf(acc0[mt][cb][r]);
          if constexpr (DUAL) C1[(size_t)gr * 128 + gc] = f2bf(acc1[mt][cb][r] + bv[cb]);
        }
      }
    }
  }
}

// ------------------------------------------------------------------
// fused per-layer GEMM dispatchers (segment switch on blockIdx.x)
// dynamic LDS = 3 * 128 * AST * 2 bytes
// ------------------------------------------------------------------
__global__ __launch_bounds__(256, 2) void layer1_kernel(
    const float* __restrict__ xc, int Mc,
    const unsigned short* __restrict__ Bc0, const unsigned short* __restrict__ Bc1,
    unsigned short* __restrict__ y_s, unsigned short* __restrict__ h1,
    const float* __restrict__ b1s,
    const float* __restrict__ xt, int Mt, const unsigned short* __restrict__ Bt_,
    unsigned short* __restrict__ y_a,
    const float* __restrict__ xcl, int Mcl, const unsigned short* __restrict__ Bcl,
    unsigned short* __restrict__ y_t, int nbC, int nbT) {
  extern __shared__ unsigned short smem[];
  unsigned short* As = smem;
  unsigned short* Bs0 = smem + 128 * AST;
  unsigned short* Bs1 = smem + 2 * 128 * AST;
  int b = blockIdx.x;
  if (b < nbC)
    gemm_body<256, true, false, false>(b, As, Bs0, Bs1, xc, Mc, Bc0, Bc1, y_s, h1, b1s);
  else if (b < nbC + nbT)
    gemm_body<128, false, false, false>(b - nbC, As, Bs0, Bs1, xt, Mt, Bt_, nullptr, y_a, nullptr, nullptr);
  else
    gemm_body<128, false, false, false>(b - nbC - nbT, As, Bs0, Bs1, xcl, Mcl, Bcl, nullptr, y_t, nullptr, nullptr);
}

__global__ __launch_bounds__(256, 2) void layer2_kernel(
    unsigned short* h1, int Mc,
    const unsigned short* __restrict__ Bc0, const unsigned short* __restrict__ Bc1,
    unsigned short* __restrict__ y_s, const float* __restrict__ b2s,
    const float* __restrict__ xt, int Mt, const unsigned short* __restrict__ Bt_,
    unsigned short* __restrict__ y_a,
    const float* __restrict__ xcl, int Mcl, const unsigned short* __restrict__ Bcl,
    unsigned short* __restrict__ y_t, int nbC, int nbT) {
  extern __shared__ unsigned short smem[];
  unsigned short* As = smem;
  unsigned short* Bs0 = smem + 128 * AST;
  unsigned short* Bs1 = smem + 2 * 128 * AST;
  int b = blockIdx.x;
  if (b < nbC)
    gemm_body<128, true, true, true>(b, As, Bs0, Bs1, h1, Mc, Bc0, Bc1, y_s, h1, b2s);
  else if (b < nbC + nbT)
    gemm_body<128, false, false, false>(b - nbC, As, Bs0, Bs1, xt, Mt, Bt_, nullptr, y_a, nullptr, nullptr);
  else
    gemm_body<128, false, false, false>(b - nbC - nbT, As, Bs0, Bs1, xcl, Mcl, Bcl, nullptr, y_t, nullptr, nullptr);
}

// ------------------------------------------------------------------
// fused CSR gather, quarter-wave per edge; h is bf16 (RMW by quarter 0)
// ------------------------------------------------------------------
__global__ __launch_bounds__(256) void gather_kernel(
    const unsigned short* __restrict__ ys, const unsigned short* __restrict__ ya,
    const unsigned short* __restrict__ yt,
    const int* __restrict__ rs_all,
    const int* __restrict__ src_s, const int* __restrict__ src_a,
    const int* __restrict__ src_t,
    const float* __restrict__ inv, unsigned short* h, int M) {
  int row = blockIdx.x * 4 + (threadIdx.x >> 6);
  if (row >= M) return;
  const int lane = threadIdx.x & 63;
  const int q = lane >> 4;
  const int col = (lane & 15) * 8;
  const int NP = M + 1;

  int b0 = rs_all[row],          e0 = rs_all[row + 1];
  int b1 = rs_all[NP + row],     e1 = rs_all[NP + row + 1];
  int b2 = rs_all[2 * NP + row], e2 = rs_all[2 * NP + row + 1];
  float sc0 = inv[row], sc1 = inv[M + row], sc2 = inv[2 * M + row];

  float acc[8];
#pragma unroll
  for (int j = 0; j < 8; ++j) acc[j] = 0.f;

  auto seg = [&](const unsigned short* __restrict__ y, const int* __restrict__ src,
                 int b, int e, float sc) {
    float s[8];
#pragma unroll
    for (int j = 0; j < 8; ++j) s[j] = 0.f;
    for (int i = b + q; i < e; i += 4) {
      int si = src[i];
      uint4 v = *(const uint4*)(y + (size_t)si * HD + col);
      s[0] += __uint_as_float(v.x << 16);
      s[1] += __uint_as_float(v.x & 0xffff0000u);
      s[2] += __uint_as_float(v.y << 16);
      s[3] += __uint_as_float(v.y & 0xffff0000u);
      s[4] += __uint_as_float(v.z << 16);
      s[5] += __uint_as_float(v.z & 0xffff0000u);
      s[6] += __uint_as_float(v.w << 16);
      s[7] += __uint_as_float(v.w & 0xffff0000u);
    }
#pragma unroll
    for (int j = 0; j < 8; ++j) acc[j] += s[j] * sc;
  };
  seg(ys, src_s, b0, e0, sc0);
  seg(ya, src_a, b1, e1, sc1);
  seg(yt, src_t, b2, e2, sc2);

#pragma unroll
  for (int j = 0; j < 8; ++j) {
    acc[j] += __shfl_xor(acc[j], 16);
    acc[j] += __shfl_xor(acc[j], 32);
  }
  if (q == 0) {
    uint4 hv = *(uint4*)(h + (size_t)row * HD + col);
    auto upd = [&](unsigned int u, float a0, float a1) {
      float lo = __uint_as_float(u << 16) + a0;
      float hi = __uint_as_float(u & 0xffff0000u) + a1;
      return (unsigned int)f2bf(lo) | ((unsigned int)f2bf(hi) << 16);
    };
    hv.x = upd(hv.x, acc[0], acc[1]);
    hv.y = upd(hv.y, acc[2], acc[3]);
    hv.z = upd(hv.z, acc[4], acc[5]);
    hv.w = upd(hv.w, acc[6], acc[7]);
    *(uint4*)(h + (size_t)row * HD + col) = hv;
  }
}

// ------------------------------------------------------------------
// fused heads: P = relu(h2)@Wht^T + bh (MFMA) -> LDS -> epilogue
// 64 rows/block, 4 waves; thread t<64 does row t's sigmoid/softmax/impl
// ------------------------------------------------------------------
__global__ __launch_bounds__(256, 4) void heads_kernel(
    const unsigned short* __restrict__ h2b, int M,
    const unsigned short* __restrict__ Wht, const float* __restrict__ bh,
    const float* __restrict__ Wm,
    float* __restrict__ out_t, float* __restrict__ out_i,
    float* __restrict__ out_m) {
  constexpr int AST_H = 136;
  __shared__ unsigned short As[64 * AST_H];
  __shared__ float Ps[64][17];
  const int t = threadIdx.x;
  const int wave = t >> 6, lane = t & 63;
  const int m0 = blockIdx.x * 64;
  const int lrow = lane & 15, lq = lane >> 4;

#pragma unroll
  for (int j = 0; j < 4; ++j) {
    int idx = j * 256 + t;
    int row = idx >> 4;
    int c8 = idx & 15;
    int gr = m0 + row;
    uint4 v = make_uint4(0, 0, 0, 0);
    if (gr < M) v = *(const uint4*)(h2b + (size_t)gr * 128 + c8 * 8);
    v.x = relu2(v.x); v.y = relu2(v.y); v.z = relu2(v.z); v.w = relu2(v.w);
    *(uint4*)&As[row * AST_H + c8 * 8] = v;
  }
  __syncthreads();

  v4f acc = (v4f)(0.f);
#pragma unroll
  for (int ks = 0; ks < 4; ++ks) {
    v8s a = *(const v8s*)&As[(wave * 16 + lrow) * AST_H + ks * 32 + lq * 8];
    v8s b = *(const v8s*)(Wht + lrow * 128 + ks * 32 + lq * 8);
    acc = __builtin_amdgcn_mfma_f32_16x16x32_bf16(a, b, acc, 0, 0, 0);
  }
  float bv = bh[lrow];
#pragma unroll
  for (int r = 0; r < 4; ++r)
    Ps[wave * 16 + lq * 4 + r][lrow] = acc[r] + bv;
  __syncthreads();

  if (t < 64) {
    int row = m0 + t;
    if (row < M) {
      float t_[5], i_[4], mb[3];
#pragma unroll
      for (int o = 0; o < 5; ++o) t_[o] = Ps[t][o];
#pragma unroll
      for (int o = 0; o < 4; ++o) i_[o] = Ps[t][5 + o];
#pragma unroll
      for (int o = 0; o < 3; ++o) mb[o] = Ps[t][9 + o];
      float tp[5];
#pragma unroll
      for (int o = 0; o < 5; ++o) tp[o] = 1.f / (1.f + __expf(-t_[o]));
      float mx = fmaxf(fmaxf(i_[0], i_[1]), fmaxf(i_[2], i_[3]));
      float ex[4], es = 0.f;
#pragma unroll
      for (int o = 0; o < 4; ++o) { ex[o] = __expf(i_[o] - mx); es += ex[o]; }
      float inv_es = 1.f / es;
      float ml[3];
#pragma unroll
      for (int o = 0; o < 3; ++o) {
        float v = mb[o];
#pragma unroll
        for (int j = 0; j < 5; ++j) v += tp[j] * Wm[(128 + j) * 3 + o];
#pragma unroll
        for (int j = 0; j < 4; ++j) v += (ex[j] * inv_es) * Wm[(133 + j) * 3 + o];
        ml[o] = v;
      }
#pragma unroll
      for (int o = 0; o < 5; ++o) out_t[(size_t)row * 5 + o] = t_[o];
#pragma unroll
      for (int o = 0; o < 4; ++o) out_i[(size_t)row * 4 + o] = i_[o];
#pragma unroll
      for (int o = 0; o < 3; ++o) out_m[(size_t)row * 3 + o] = ml[o];
    }
  }
}

// ------------------------------------------------------------------
extern "C" void kernel_launch(void* const* d_in, const int* in_sizes, int n_in,
                              void* d_out, int out_size, void* d_ws, size_t ws_size,
                              hipStream_t stream) {
  const float* x_comment = (const float*)d_in[0];
  const float* x_topic   = (const float*)d_in[1];
  const float* x_claim   = (const float*)d_in[2];
  const float* c1s_Wl = (const float*)d_in[3];
  const float* c1s_bl = (const float*)d_in[4];
  const float* c1s_Wr = (const float*)d_in[5];
  const float* c1a_Wl = (const float*)d_in[6];
  const float* c1a_bl = (const float*)d_in[7];
  const float* c1a_Wr = (const float*)d_in[8];
  const float* c1t_Wl = (const float*)d_in[9];
  const float* c1t_bl = (const float*)d_in[10];
  const float* c1t_Wr = (const float*)d_in[11];
  const float* c2s_Wl = (const float*)d_in[12];
  const float* c2s_bl = (const float*)d_in[13];
  const float* c2s_Wr = (const float*)d_in[14];
  const float* c2a_Wl = (const float*)d_in[15];
  const float* c2a_bl = (const float*)d_in[16];
  const float* c2a_Wr = (const float*)d_in[17];
  const float* c2t_Wl = (const float*)d_in[18];
  const float* c2t_bl = (const float*)d_in[19];
  const float* c2t_Wr = (const float*)d_in[20];
  const float* Wt = (const float*)d_in[21];
  const float* bt = (const float*)d_in[22];
  const float* Wi = (const float*)d_in[23];
  const float* bi = (const float*)d_in[24];
  const float* Wm = (const float*)d_in[25];
  const float* bm = (const float*)d_in[26];
  const int* ei_sim = (const int*)d_in[27];
  const int* ei_ab  = (const int*)d_in[28];
  const int* ei_tg  = (const int*)d_in[29];

  const int E_sim = in_sizes[27] / 2;
  const int E_ab  = in_sizes[28] / 2;
  const int E_tg  = in_sizes[29] / 2;
  const int N_T = in_sizes[1] / 128;
  const int N_CL = in_sizes[2] / 128;

  float* ws = (float*)d_ws;
  unsigned short* h1 = (unsigned short*)ws;                // 100000*128 bf16
  unsigned short* y_s = (unsigned short*)(ws + 12800000);  // 100000*128 bf16
  unsigned short* y_a = (unsigned short*)(ws + 19200000);  // 5000*128 bf16
  unsigned short* y_t = (unsigned short*)(ws + 19520000);  // 20000*128 bf16
  int*   cnt    = (int*)(ws + 20800000);                   // 3*N_C
  float* inv    = ws + 21100000;                           // 3*N_C
  int*   rs_all = (int*)(ws + 21400000);                   // 3*(N_C+1)
  int*   src_s  = (int*)(ws + 21700016);                   // E_sim
  int*   src_a  = (int*)(ws + 22300016);                   // E_ab
  int*   src_t  = (int*)(ws + 22600016);                   // E_tg
  int*   part   = (int*)(ws + 22900016);                   // 3*128
  float* b1s    = ws + 22900416;
  float* b2s    = ws + 22900544;
  unsigned short* Bt_c1s = (unsigned short*)(ws + 22900672);  // 128x256
  unsigned short* Bt_W1s = Bt_c1s + 32768;                    // 128x256
  unsigned short* Bt_c1a = Bt_W1s + 32768;                    // 128x128
  unsigned short* Bt_c1t = Bt_c1a + 16384;
  unsigned short* Bt_c2s = Bt_c1t + 16384;
  unsigned short* Bt_W2s = Bt_c2s + 16384;
  unsigned short* Bt_c2a = Bt_W2s + 16384;
  unsigned short* Bt_c2t = Bt_c2a + 16384;
  unsigned short* Wht = (unsigned short*)(ws + 24600000);     // 16x128 bf16
  float* bh     = ws + 24601100;                              // 16

  const int nbS = (N_C + SCAN_CHUNK - 1) / SCAN_CHUNK;
  const int ebx = (E_sim + 255) / 256;
  const int nbC = (N_C + 127) / 128;
  const int nbT = (N_T + 127) / 128;
  const int nbCl = (N_CL + 127) / 128;
  const size_t lds_bytes = 3 * 128 * AST * sizeof(unsigned short);  // 55296

  // ---- weight prep ----
  prep_weights<<<dim3(128, 10), 256, 0, stream>>>(
      c1s_Wl, c1s_Wr, c1a_Wr, c1t_Wr, c1a_Wl, c1t_Wl,
      c2s_Wl, c2s_Wr, c2a_Wr, c2t_Wr, c2a_Wl, c2t_Wl,
      c1s_bl, c1a_bl, c1t_bl, c2s_bl, c2a_bl, c2t_bl,
      Wt, bt, Wi, bi, Wm, bm,
      Bt_c1s, Bt_W1s, Bt_c1a, Bt_c1t, Bt_c2s, Bt_W2s, Bt_c2a, Bt_c2t,
      Wht, b1s, b2s, bh);

  // ---- degree histogram + CSR build ----
  hipMemsetAsync(cnt, 0, 3 * N_C * sizeof(int), stream);
  count3_kernel<<<dim3(ebx, 3), 256, 0, stream>>>(ei_sim, E_sim, ei_ab, E_ab, ei_tg, E_tg, cnt);
  scan_phaseA<<<dim3(nbS, 3), 256, 0, stream>>>(cnt, part, inv, N_C);
  scan_phaseB<<<dim3(1, 3), 256, 0, stream>>>(part, nbS);
  scan_phaseC<<<dim3(nbS, 3), 256, 0, stream>>>(cnt, part, rs_all, N_C);
  set_totals<<<1, 64, 0, stream>>>(rs_all, E_sim, E_ab, E_tg, N_C);
  place3_kernel<<<dim3(ebx, 3), 256, 0, stream>>>(
      ei_sim, E_sim, ei_ab, E_ab, ei_tg, E_tg, rs_all, cnt, src_s, src_a, src_t, N_C);

  // ---------------- layer 1 (fused 3 GEMMs) ----------------
  layer1_kernel<<<nbC + nbT + nbCl, 256, lds_bytes, stream>>>(
      x_comment, N_C, Bt_c1s, Bt_W1s, y_s, h1, b1s,
      x_topic, N_T, Bt_c1a, y_a,
      x_claim, N_CL, Bt_c1t, y_t, nbC, nbT);

  gather_kernel<<<(N_C + 3) / 4, 256, 0, stream>>>(
      y_s, y_a, y_t, rs_all, src_s, src_a, src_t, inv, h1, N_C);

  // ---------------- layer 2 (fused 3 GEMMs, h in-place bf16) --------
  layer2_kernel<<<nbC + nbT + nbCl, 256, lds_bytes, stream>>>(
      h1, N_C, Bt_c2s, Bt_W2s, y_s, b2s,
      x_topic, N_T, Bt_c2a, y_a,
      x_claim, N_CL, Bt_c2t, y_t, nbC, nbT);

  gather_kernel<<<(N_C + 3) / 4, 256, 0, stream>>>(
      y_s, y_a, y_t, rs_all, src_s, src_a, src_t, inv, h1, N_C);

  // ---------------- heads (fully fused) ----------------
  float* out = (float*)d_out;
  heads_kernel<<<(N_C + 63) / 64, 256, 0, stream>>>(
      h1, N_C, Wht, bh, Wm,
      out, out + (size_t)N_C * 5, out + (size_t)N_C * 9);
}